// Round 3
// baseline (827.480 us; speedup 1.0000x reference)
//
#include <hip/hip_runtime.h>

#define NROWS 65536
#define EDIM 256
#define NQ 8
#define NE 512
#define DSUB 32
#define RPB 128           // rows per block

// ===== numpy float32 bit-exact building blocks =====
// (all strict IEEE f32 ops via *_rn intrinsics: immune to -ffp-contract)

// numpy FLOAT_pairwise_sum for n=32, contiguous (8-accumulator pattern,
// scalar C source in numpy -> ISA-independent order).
__device__ __forceinline__ float np_pairwise32(const float* p) {
  float r0 = p[0], r1 = p[1], r2 = p[2], r3 = p[3];
  float r4 = p[4], r5 = p[5], r6 = p[6], r7 = p[7];
  r0 = __fadd_rn(r0, p[8]);  r1 = __fadd_rn(r1, p[9]);
  r2 = __fadd_rn(r2, p[10]); r3 = __fadd_rn(r3, p[11]);
  r4 = __fadd_rn(r4, p[12]); r5 = __fadd_rn(r5, p[13]);
  r6 = __fadd_rn(r6, p[14]); r7 = __fadd_rn(r7, p[15]);
  r0 = __fadd_rn(r0, p[16]); r1 = __fadd_rn(r1, p[17]);
  r2 = __fadd_rn(r2, p[18]); r3 = __fadd_rn(r3, p[19]);
  r4 = __fadd_rn(r4, p[20]); r5 = __fadd_rn(r5, p[21]);
  r6 = __fadd_rn(r6, p[22]); r7 = __fadd_rn(r7, p[23]);
  r0 = __fadd_rn(r0, p[24]); r1 = __fadd_rn(r1, p[25]);
  r2 = __fadd_rn(r2, p[26]); r3 = __fadd_rn(r3, p[27]);
  r4 = __fadd_rn(r4, p[28]); r5 = __fadd_rn(r5, p[29]);
  r6 = __fadd_rn(r6, p[30]); r7 = __fadd_rn(r7, p[31]);
  float a = __fadd_rn(__fadd_rn(r0, r1), __fadd_rn(r2, r3));
  float b = __fadd_rn(__fadd_rn(r4, r5), __fadd_rn(r6, r7));
  return __fadd_rn(a, b);
}

// numpy einsum sum_of_products (contraction d=32, contiguous both operands),
// baseline SSE3 build: 4-lane vectors, NO fma (mul then add), x4-unrolled
// chain adds sub-blocks in order 12..15, 8..11, 4..7, 0..3, 28..31, 24..27,
// 20..23, 16..19; horizontal hadd: (t0+t1)+(t2+t3).
__device__ __forceinline__ float np_einsum_dot32(const float* x, const float* y) {
  float t[4];
  #pragma unroll
  for (int j = 0; j < 4; ++j) {
    float a = __fmul_rn(x[12 + j], y[12 + j]);
    a = __fadd_rn(__fmul_rn(x[8 + j],  y[8 + j]),  a);
    a = __fadd_rn(__fmul_rn(x[4 + j],  y[4 + j]),  a);
    a = __fadd_rn(__fmul_rn(x[0 + j],  y[0 + j]),  a);
    a = __fadd_rn(__fmul_rn(x[28 + j], y[28 + j]), a);
    a = __fadd_rn(__fmul_rn(x[24 + j], y[24 + j]), a);
    a = __fadd_rn(__fmul_rn(x[20 + j], y[20 + j]), a);
    a = __fadd_rn(__fmul_rn(x[16 + j], y[16 + j]), a);
    t[j] = a;
  }
  return __fadd_rn(__fadd_rn(t[0], t[1]), __fadd_rn(t[2], t[3]));
}

// ===== per-code squared norm, numpy semantics =====
__global__ void vq_cnorm_kernel(const float* __restrict__ cb, float* __restrict__ cnorm) {
  int q = blockIdx.x;
  for (int k = threadIdx.x; k < NE; k += blockDim.x) {
    const float* c = cb + ((size_t)(q * NE + k)) * DSUB;
    float p[DSUB];
    #pragma unroll
    for (int d = 0; d < DSUB; ++d) p[d] = __fmul_rn(c[d], c[d]);
    cnorm[q * NE + k] = np_pairwise32(p);
  }
}

__global__ __launch_bounds__(256) void vq_main_kernel(
    const float* __restrict__ z, const float* __restrict__ cb,
    const float* __restrict__ cnorm,
    float* __restrict__ out_zq, float* __restrict__ out_idx,
    double* __restrict__ partials) {
  const int q = blockIdx.y;
  const int row0 = blockIdx.x * RPB;
  const int tid = threadIdx.x;
  const int wave = tid >> 6;
  const int lane = tid & 63;
  const int k0 = wave * 128 + lane * 2;   // 2 codes per lane, 512 per block

  // this lane's two codebook codes resident in registers
  float c0[DSUB], c1[DSUB];
  {
    const float4* cb4 = (const float4*)(cb + ((size_t)(q * NE + k0)) * DSUB);
    #pragma unroll
    for (int i = 0; i < 8; ++i) {
      float4 v = cb4[i];
      c0[4*i+0] = v.x; c0[4*i+1] = v.y; c0[4*i+2] = v.z; c0[4*i+3] = v.w;
    }
    #pragma unroll
    for (int i = 0; i < 8; ++i) {
      float4 v = cb4[8+i];
      c1[4*i+0] = v.x; c1[4*i+1] = v.y; c1[4*i+2] = v.z; c1[4*i+3] = v.w;
    }
  }
  const float cn0 = cnorm[q * NE + k0];
  const float cn1 = cnorm[q * NE + k0 + 1];

  __shared__ float s_A[RPB];     // numpy ||z_sub||^2 per row
  __shared__ float s_val[4];
  __shared__ int   s_idx[4];

  // precompute A for all rows of this block (numpy pairwise tree)
  if (tid < RPB) {
    const float* zrow = z + (size_t)(row0 + tid) * EDIM + q * DSUB;
    float p[DSUB];
    #pragma unroll
    for (int d = 0; d < DSUB; ++d) {
      float v = zrow[d];
      p[d] = __fmul_rn(v, v);
    }
    s_A[tid] = np_pairwise32(p);
  }
  __syncthreads();

  double lacc = 0.0;   // loss partial (wave 0, lanes 0..31 only)

  for (int r = 0; r < RPB; ++r) {
    const int n = row0 + r;
    const float* zrow = z + (size_t)n * EDIM + q * DSUB;
    float zr[DSUB];
    {
      const float4* z4 = (const float4*)zrow;   // wave-uniform address
      #pragma unroll
      for (int i = 0; i < 8; ++i) {
        float4 v = z4[i];
        zr[4*i+0] = v.x; zr[4*i+1] = v.y; zr[4*i+2] = v.z; zr[4*i+3] = v.w;
      }
    }
    const float A = s_A[r];

    // numpy-bit-exact d2 = fl(fl(A + B_k) - fl(2*E_k)) for this lane's codes
    const float e0 = np_einsum_dot32(zr, c0);
    const float e1 = np_einsum_dot32(zr, c1);
    const float d0 = __fsub_rn(__fadd_rn(A, cn0), __fadd_rn(e0, e0));
    const float d1 = __fsub_rn(__fadd_rn(A, cn1), __fadd_rn(e1, e1));

    // first-occurrence argmin (tie -> lowest k), lane-local then reductions
    float v = d0; int k = k0;
    if (d1 < v) { v = d1; k = k0 + 1; }
    #pragma unroll
    for (int off = 32; off > 0; off >>= 1) {
      float ov = __shfl_xor(v, off);
      int   ok = __shfl_xor(k, off);
      if (ov < v || (ov == v && ok < k)) { v = ov; k = ok; }
    }
    if (lane == 0) { s_val[wave] = v; s_idx[wave] = k; }
    __syncthreads();
    float fv = s_val[0]; int fk = s_idx[0];
    #pragma unroll
    for (int w = 1; w < 4; ++w) {
      float wv = s_val[w]; int wk = s_idx[w];
      if (wv < fv || (wv == fv && wk < fk)) { fv = wv; fk = wk; }
    }

    // ---- outputs (wave 0) ----
    if (wave == 0) {
      if (lane < DSUB) {
        float cv = cb[((size_t)(q * NE + fk)) * DSUB + lane];
        float zv = zr[lane];   // careful: lane<32 so zr index == lane... but zr is per-thread
        // zr holds the full row for every thread; lane-th element is zrow[lane]
        cv = cb[((size_t)(q * NE + fk)) * DSUB + lane];
        zv = zrow[lane];
        out_zq[(size_t)n * EDIM + q * DSUB + lane] = cv;
        double diff = (double)cv - (double)zv;
        lacc = fma(diff, diff, lacc);
      }
      if (lane == 0) out_idx[(size_t)n * NQ + q] = (float)fk;
    }
    __syncthreads();   // protect s_val/s_idx reuse next iteration
  }

  // deterministic per-block loss partial (only wave 0 holds nonzero)
  if (wave == 0) {
    #pragma unroll
    for (int off = 32; off > 0; off >>= 1) lacc += __shfl_xor(lacc, off);
    if (lane == 0) partials[blockIdx.y * gridDim.x + blockIdx.x] = lacc;
  }
}

__global__ void vq_loss_kernel(const double* __restrict__ partials, int np,
                               float* __restrict__ out_loss) {
  __shared__ double sh[256];
  double s = 0.0;
  for (int i = threadIdx.x; i < np; i += 256) s += partials[i];
  sh[threadIdx.x] = s;
  __syncthreads();
  for (int st = 128; st > 0; st >>= 1) {
    if ((int)threadIdx.x < st) sh[threadIdx.x] += sh[threadIdx.x + st];
    __syncthreads();
  }
  if (threadIdx.x == 0) {
    double m = sh[0] / 16777216.0;   // mean over 8*65536*32 elements
    *out_loss = (float)(1.25 * m);   // BETA*m + m
  }
}

extern "C" void kernel_launch(void* const* d_in, const int* in_sizes, int n_in,
                              void* d_out, int out_size, void* d_ws, size_t ws_size,
                              hipStream_t stream) {
  const float* z  = (const float*)d_in[0];
  const float* cb = (const float*)d_in[1];
  float* out = (float*)d_out;
  float* out_zq   = out;
  float* out_loss = out + (size_t)NROWS * EDIM;           // element 16777216
  float* out_idx  = out + (size_t)NROWS * EDIM + 1;       // elements 16777217..

  float*  cnorm    = (float*)d_ws;                                  // 16 KB
  double* partials = (double*)((char*)d_ws + 16384);                // 4096 * 8 B

  vq_cnorm_kernel<<<NQ, 256, 0, stream>>>(cb, cnorm);
  dim3 grid(NROWS / RPB, NQ);
  vq_main_kernel<<<grid, 256, 0, stream>>>(z, cb, cnorm, out_zq, out_idx, partials);
  vq_loss_kernel<<<1, 256, 0, stream>>>(partials, (NROWS / RPB) * NQ, out_loss);
}

// Round 4
// 344.353 us; speedup vs baseline: 2.4030x; 2.4030x over previous
//
#include <hip/hip_runtime.h>

#define NROWS 65536
#define EDIM 256
#define NQ 8
#define NE 512
#define DSUB 32
#define RPB 64            // rows per block
#define MARGIN 1e-4f

typedef __attribute__((ext_vector_type(8))) short short8;
typedef __attribute__((ext_vector_type(4))) float f32x4;

// round-to-nearest-even f32 -> bf16 (bit-exact, deterministic)
static __device__ __forceinline__ unsigned short bf16_rne(float f) {
  unsigned int u = __float_as_uint(f);
  unsigned int r = 0x7FFFu + ((u >> 16) & 1u);
  return (unsigned short)((u + r) >> 16);
}
static __device__ __forceinline__ float bf16_f32(unsigned short h) {
  return __uint_as_float(((unsigned int)h) << 16);
}

// ===== numpy float32 bit-exact building blocks (validated round 3) =====
__device__ __forceinline__ float np_pairwise32(const float* p) {
  float r0 = p[0], r1 = p[1], r2 = p[2], r3 = p[3];
  float r4 = p[4], r5 = p[5], r6 = p[6], r7 = p[7];
  r0 = __fadd_rn(r0, p[8]);  r1 = __fadd_rn(r1, p[9]);
  r2 = __fadd_rn(r2, p[10]); r3 = __fadd_rn(r3, p[11]);
  r4 = __fadd_rn(r4, p[12]); r5 = __fadd_rn(r5, p[13]);
  r6 = __fadd_rn(r6, p[14]); r7 = __fadd_rn(r7, p[15]);
  r0 = __fadd_rn(r0, p[16]); r1 = __fadd_rn(r1, p[17]);
  r2 = __fadd_rn(r2, p[18]); r3 = __fadd_rn(r3, p[19]);
  r4 = __fadd_rn(r4, p[20]); r5 = __fadd_rn(r5, p[21]);
  r6 = __fadd_rn(r6, p[22]); r7 = __fadd_rn(r7, p[23]);
  r0 = __fadd_rn(r0, p[24]); r1 = __fadd_rn(r1, p[25]);
  r2 = __fadd_rn(r2, p[26]); r3 = __fadd_rn(r3, p[27]);
  r4 = __fadd_rn(r4, p[28]); r5 = __fadd_rn(r5, p[29]);
  r6 = __fadd_rn(r6, p[30]); r7 = __fadd_rn(r7, p[31]);
  float a = __fadd_rn(__fadd_rn(r0, r1), __fadd_rn(r2, r3));
  float b = __fadd_rn(__fadd_rn(r4, r5), __fadd_rn(r6, r7));
  return __fadd_rn(a, b);
}

__device__ __forceinline__ float np_einsum_dot32(const float* x, const float* y) {
  float t[4];
  #pragma unroll
  for (int j = 0; j < 4; ++j) {
    float a = __fmul_rn(x[12 + j], y[12 + j]);
    a = __fadd_rn(__fmul_rn(x[8 + j],  y[8 + j]),  a);
    a = __fadd_rn(__fmul_rn(x[4 + j],  y[4 + j]),  a);
    a = __fadd_rn(__fmul_rn(x[0 + j],  y[0 + j]),  a);
    a = __fadd_rn(__fmul_rn(x[28 + j], y[28 + j]), a);
    a = __fadd_rn(__fmul_rn(x[24 + j], y[24 + j]), a);
    a = __fadd_rn(__fmul_rn(x[20 + j], y[20 + j]), a);
    a = __fadd_rn(__fmul_rn(x[16 + j], y[16 + j]), a);
    t[j] = a;
  }
  return __fadd_rn(__fadd_rn(t[0], t[1]), __fadd_rn(t[2], t[3]));
}

// ===== per-code squared norm, numpy semantics (-> ws) =====
__global__ void vq_cnorm_kernel(const float* __restrict__ cb, float* __restrict__ cnorm) {
  int q = blockIdx.x;
  for (int k = threadIdx.x; k < NE; k += blockDim.x) {
    const float* c = cb + ((size_t)(q * NE + k)) * DSUB;
    float p[DSUB];
    #pragma unroll
    for (int d = 0; d < DSUB; ++d) p[d] = __fmul_rn(c[d], c[d]);
    cnorm[q * NE + k] = np_pairwise32(p);
  }
}

__global__ __launch_bounds__(256) void vq_mfma_kernel(
    const float* __restrict__ z, const float* __restrict__ cb,
    const float* __restrict__ cnorm,
    float* __restrict__ out_zq, float* __restrict__ out_idx,
    float* __restrict__ partials) {
  __shared__ unsigned short s_cb[2][4][NE][8];  // [hi/lo][g][code][e] = 64 KB
  __shared__ float s_z[RPB][DSUB];              // 8 KB
  __shared__ float s_cn[NE];                    // 2 KB
  __shared__ unsigned int s_res[4][16];
  __shared__ double s_part[4];

  const int q    = blockIdx.y;
  const int row0 = blockIdx.x * RPB;
  const int tid  = threadIdx.x;
  const int w    = tid >> 6;
  const int lane = tid & 63;
  const int g    = lane >> 4;
  const int c16  = lane & 15;

  // ---- stage codebook bf16 hi/lo split into LDS ([g][code][8] layout) ----
  {
    const float4* cbq = (const float4*)(cb + (size_t)q * NE * DSUB);
    #pragma unroll 1
    for (int it = 0; it < 16; ++it) {
      int fi = it * 256 + tid;            // float4 index 0..4095
      float4 v = cbq[fi];
      int k  = fi >> 3;                   // code index
      int d0 = (fi & 7) * 4;              // 0,4,...,28 (stays within one 8-group)
      int gg = d0 >> 3, e0 = d0 & 7;
      float vv[4] = {v.x, v.y, v.z, v.w};
      unsigned long long ph = 0ull, pl = 0ull;
      #pragma unroll
      for (int j = 0; j < 4; ++j) {
        unsigned short hh = bf16_rne(vv[j]);
        unsigned short ll = bf16_rne(__fsub_rn(vv[j], bf16_f32(hh)));  // exact residual split
        ph |= ((unsigned long long)hh) << (16 * j);
        pl |= ((unsigned long long)ll) << (16 * j);
      }
      *(unsigned long long*)&s_cb[0][gg][k][e0] = ph;
      *(unsigned long long*)&s_cb[1][gg][k][e0] = pl;
    }
  }
  // ---- stage z tile (64 rows x 32 dims f32) ----
  {
    const float4* z4 = (const float4*)z;
    #pragma unroll
    for (int it = 0; it < 2; ++it) {
      int fi = it * 256 + tid;            // 0..511
      int r = fi >> 3, j = fi & 7;
      float4 v = z4[(size_t)(row0 + r) * (EDIM / 4) + q * 8 + j];
      *(float4*)&s_z[r][j * 4] = v;
    }
  }
  // ---- stage cn ----
  if (tid < 128) ((float4*)s_cn)[tid] = ((const float4*)(cnorm + q * NE))[tid];
  __syncthreads();

  // ---- A fragments: this wave's 16 rows, bf16 hi/lo split ----
  short8 ah, al;
  {
    const float* zr = &s_z[w * 16 + c16][g * 8];
    #pragma unroll
    for (int i = 0; i < 8; ++i) {
      float zv = zr[i];
      unsigned short hh = bf16_rne(zv);
      unsigned short ll = bf16_rne(__fsub_rn(zv, bf16_f32(hh)));
      ah[i] = (short)hh;
      al[i] = (short)ll;
    }
  }

  // ---- MFMA screen over all 32 code-tiles, tracking (min1, idx1, min2) ----
  float v1[4] = {1e30f, 1e30f, 1e30f, 1e30f};
  float v2[4] = {1e30f, 1e30f, 1e30f, 1e30f};
  int   i1[4] = {0x7FFFFFFF, 0x7FFFFFFF, 0x7FFFFFFF, 0x7FFFFFFF};

  for (int ct = 0; ct < 32; ++ct) {
    int code = ct * 16 + c16;
    short8 bh = *(const short8*)&s_cb[0][g][code][0];
    short8 bl = *(const short8*)&s_cb[1][g][code][0];
    f32x4 acc = {0.f, 0.f, 0.f, 0.f};
    acc = __builtin_amdgcn_mfma_f32_16x16x32_bf16(ah, bh, acc, 0, 0, 0);
    acc = __builtin_amdgcn_mfma_f32_16x16x32_bf16(al, bh, acc, 0, 0, 0);
    acc = __builtin_amdgcn_mfma_f32_16x16x32_bf16(ah, bl, acc, 0, 0, 0);
    float cnv = s_cn[code];
    #pragma unroll
    for (int j = 0; j < 4; ++j) {
      float val = fmaf(-2.0f, acc[j], cnv);        // screen value (not numpy-exact)
      v2[j] = fminf(v2[j], fmaxf(v1[j], val));     // second-smallest
      bool lt = val < v1[j];
      i1[j] = lt ? code : i1[j];                   // strict < keeps lowest idx
      v1[j] = fminf(v1[j], val);
    }
  }

  // ---- cross-lane reduce within 16-lane group (rows 4g+j live there) ----
  #pragma unroll
  for (int off = 1; off <= 8; off <<= 1) {
    #pragma unroll
    for (int j = 0; j < 4; ++j) {
      float ov1 = __shfl_xor(v1[j], off);
      float ov2 = __shfl_xor(v2[j], off);
      int   oi1 = __shfl_xor(i1[j], off);
      bool take = (ov1 < v1[j]) || (ov1 == v1[j] && oi1 < i1[j]);
      float loser = take ? v1[j] : ov1;
      v2[j] = fminf(fminf(v2[j], ov2), loser);
      v1[j] = take ? ov1 : v1[j];
      i1[j] = take ? oi1 : i1[j];
    }
  }
  if (c16 < 4) {
    int j = c16;
    unsigned int slow = (v2[j] <= v1[j] + MARGIN) ? 0x80000000u : 0u;
    s_res[w][g * 4 + j] = slow | (unsigned int)i1[j];
  }

  // ---- rare slow path: full-wave numpy-bit-exact rescan of ambiguous rows ----
  for (int rr = 0; rr < 16; ++rr) {
    unsigned int res = s_res[w][rr];          // wave-uniform
    if (res & 0x80000000u) {
      int row_local = w * 16 + rr;
      float zreg[DSUB];
      #pragma unroll
      for (int d = 0; d < DSUB; ++d) zreg[d] = s_z[row_local][d];
      float p[DSUB];
      #pragma unroll
      for (int d = 0; d < DSUB; ++d) p[d] = __fmul_rn(zreg[d], zreg[d]);
      float A = np_pairwise32(p);
      float bv = 1e30f; int bk = 0x7FFFFFFF;
      #pragma unroll 1
      for (int i = 0; i < 8; ++i) {
        int k = lane * 8 + i;
        const float4* cp = (const float4*)(cb + ((size_t)(q * NE + k)) * DSUB);
        float creg[DSUB];
        #pragma unroll
        for (int j = 0; j < 8; ++j) {
          float4 cv = cp[j];
          creg[4 * j + 0] = cv.x; creg[4 * j + 1] = cv.y;
          creg[4 * j + 2] = cv.z; creg[4 * j + 3] = cv.w;
        }
        float e = np_einsum_dot32(zreg, creg);
        float d2 = __fsub_rn(__fadd_rn(A, s_cn[k]), __fadd_rn(e, e));
        if (d2 < bv) { bv = d2; bk = k; }     // ascending k keeps lowest on tie
      }
      #pragma unroll
      for (int off = 1; off <= 32; off <<= 1) {
        float ov = __shfl_xor(bv, off);
        int   ok = __shfl_xor(bk, off);
        if (ov < bv || (ov == bv && ok < bk)) { bv = ov; bk = ok; }
      }
      if (lane == 0) s_res[w][rr] = (unsigned int)bk;
    }
  }

  // ---- outputs: z_q (f32 code values), idx, f64 loss partial ----
  double lacc = 0.0;
  #pragma unroll
  for (int ii = 0; ii < 2; ++ii) {
    int rr = ii * 8 + (lane >> 3);
    int j8 = lane & 7;
    int row_local = w * 16 + rr;
    int n = row0 + row_local;
    int kstar = (int)(s_res[w][rr] & 0x7FFFFFFFu);
    float4 cv = ((const float4*)(cb + ((size_t)(q * NE + kstar)) * DSUB))[j8];
    *(float4*)(out_zq + (size_t)n * EDIM + q * DSUB + j8 * 4) = cv;
    const float* zp = &s_z[row_local][j8 * 4];
    double d0 = (double)cv.x - (double)zp[0];
    double d1 = (double)cv.y - (double)zp[1];
    double d2 = (double)cv.z - (double)zp[2];
    double d3 = (double)cv.w - (double)zp[3];
    lacc = fma(d0, d0, lacc); lacc = fma(d1, d1, lacc);
    lacc = fma(d2, d2, lacc); lacc = fma(d3, d3, lacc);
    if (j8 == 0) out_idx[(size_t)n * NQ + q] = (float)kstar;
  }

  #pragma unroll
  for (int off = 1; off < 64; off <<= 1) lacc += __shfl_xor(lacc, off);
  if (lane == 0) s_part[w] = lacc;
  __syncthreads();
  if (tid == 0)
    partials[blockIdx.y * gridDim.x + blockIdx.x] =
        (float)(s_part[0] + s_part[1] + s_part[2] + s_part[3]);
}

__global__ void vq_loss_kernel(const float* __restrict__ partials, int np,
                               float* __restrict__ out_loss) {
  __shared__ double sh[256];
  double s = 0.0;
  for (int i = threadIdx.x; i < np; i += 256) s += (double)partials[i];
  sh[threadIdx.x] = s;
  __syncthreads();
  for (int st = 128; st > 0; st >>= 1) {
    if ((int)threadIdx.x < st) sh[threadIdx.x] += sh[threadIdx.x + st];
    __syncthreads();
  }
  if (threadIdx.x == 0) {
    double m = sh[0] / 16777216.0;      // mean over 8*65536*32 elements
    *out_loss = (float)(1.25 * m);      // BETA*m + m
  }
}

extern "C" void kernel_launch(void* const* d_in, const int* in_sizes, int n_in,
                              void* d_out, int out_size, void* d_ws, size_t ws_size,
                              hipStream_t stream) {
  const float* z  = (const float*)d_in[0];
  const float* cb = (const float*)d_in[1];
  float* out = (float*)d_out;
  float* out_zq   = out;
  float* out_loss = out + (size_t)NROWS * EDIM;       // element 16777216
  float* out_idx  = out + (size_t)NROWS * EDIM + 1;   // elements 16777217..

  float* cnorm    = (float*)d_ws;                     // 16 KB
  float* partials = (float*)((char*)d_ws + 16384);    // 8192 * 4 B = 32 KB

  vq_cnorm_kernel<<<NQ, 256, 0, stream>>>(cb, cnorm);
  dim3 grid(NROWS / RPB, NQ);
  vq_mfma_kernel<<<grid, 256, 0, stream>>>(z, cb, cnorm, out_zq, out_idx, partials);
  vq_loss_kernel<<<1, 256, 0, stream>>>(partials, (NROWS / RPB) * NQ, out_loss);
}